// Round 1
// baseline (2657.814 us; speedup 1.0000x reference)
//
#include <hip/hip_runtime.h>

#define NT   512
#define HID  64
#define WST  68                   // padded LDS row stride (floats), keeps 16B align, spreads banks
#define IMPN (2048 * 512)

__device__ __forceinline__ float fsig(float x) {
    // sigmoid(x) = 1/(1+e^-x); v_exp+v_rcp, ~1e-7 rel err, graceful at +-inf
    return __builtin_amdgcn_rcpf(1.0f + __expf(-x));
}
__device__ __forceinline__ float ftanh(float x) {
    // tanh(x) = 2*sigmoid(2x)-1
    return 2.0f * __builtin_amdgcn_rcpf(1.0f + __expf(-2.0f * x)) - 1.0f;
}

// grid = 512 blocks x 256 threads. blocks 0..255: forward, 256..511: backward.
// Each block: 4 waves; each wave handles 2 sequences (half-wave per sequence).
// Lane (j2 = lane&31) of its half owns hidden units j2 and j2+32, and gate rows
// {j2, j2+32} (r), {64+j2, 64+j2+32} (z), {128+...} (n).
__global__ __launch_bounds__(256) void brits_rnn(
    const float* __restrict__ input,
    const float* __restrict__ gW_f, const float* __restrict__ gb_f,
    const float* __restrict__ rW_f, const float* __restrict__ rb_f,
    const float* __restrict__ fcW_f, const float* __restrict__ fcb_f,
    const float* __restrict__ Wih_f, const float* __restrict__ bih_f,
    const float* __restrict__ Whh_f, const float* __restrict__ bhh_f,
    const float* __restrict__ gW_b, const float* __restrict__ gb_b,
    const float* __restrict__ rW_b, const float* __restrict__ rb_b,
    const float* __restrict__ fcW_b, const float* __restrict__ fcb_b,
    const float* __restrict__ Wih_b, const float* __restrict__ bih_b,
    const float* __restrict__ Whh_b, const float* __restrict__ bhh_b,
    float* __restrict__ out, float* __restrict__ ws)
{
    __shared__ __align__(16) float sWhh[192 * WST];
    __shared__ __align__(16) float hbuf[2][8][HID];   // double-buffered per-seq h

    const int tid  = threadIdx.x;
    const int dir  = blockIdx.x >> 8;       // 0 fwd, 1 bwd
    const int bblk = blockIdx.x & 255;
    const int wave = tid >> 6;
    const int lane = tid & 63;
    const int j2   = lane & 31;
    const int half = lane >> 5;
    const int sidx = wave * 2 + half;        // 0..7 within block
    const int batch = bblk * 8 + sidx;       // 0..2047

    const float* gW  = dir ? gW_b  : gW_f;
    const float* gb  = dir ? gb_b  : gb_f;
    const float* rW  = dir ? rW_b  : rW_f;
    const float* rb  = dir ? rb_b  : rb_f;
    const float* fcW = dir ? fcW_b : fcW_f;
    const float* fcb = dir ? fcb_b : fcb_f;
    const float* Wih = dir ? Wih_b : Wih_f;
    const float* bih = dir ? bih_b : bih_f;
    const float* Whh = dir ? Whh_b : Whh_f;
    const float* bhh = dir ? bhh_b : bhh_f;

    // stage Whh (192x64) into LDS, padded row stride
    for (int i = tid; i < 192 * HID; i += 256) {
        int row = i >> 6, col = i & 63;
        sWhh[row * WST + col] = Whh[i];
    }

    const int jA = j2, jB = j2 + 32;
    const float gw0 = gW[jA], gw1 = gW[jB];
    const float gb0 = gb[jA], gb1 = gb[jB];
    const float rw0 = rW[jA], rw1 = rW[jB];
    const float rbv = rb[0];

    int rows[6] = { jA, jB, 64 + jA, 64 + jB, 128 + jA, 128 + jB };
    float wx[6], wm[6];
    int rowoff[6];
#pragma unroll
    for (int k = 0; k < 6; ++k) {
        wx[k] = Wih[rows[k] * 2 + 0];
        wm[k] = Wih[rows[k] * 2 + 1];
        rowoff[k] = rows[k] * WST;
    }
    // r,z rows: bih+bhh can be pre-summed (gate arg = gi+gh). n rows must stay split:
    // n = tanh(gi_n + r * (gh_n)), gh_n includes bhh.
    const float bs0 = bih[rows[0]] + bhh[rows[0]];
    const float bs1 = bih[rows[1]] + bhh[rows[1]];
    const float bs2 = bih[rows[2]] + bhh[rows[2]];
    const float bs3 = bih[rows[3]] + bhh[rows[3]];
    const float bihN0 = bih[rows[4]], bihN1 = bih[rows[5]];
    const float bhhN0 = bhh[rows[4]], bhhN1 = bhh[rows[5]];

    const float* inp_b = input + (size_t)batch * (6 * NT);   // [ch][t] for this batch
    float* impOut = out + 2048 + (size_t)dir * IMPN + (size_t)batch * NT;

    float h0 = 0.0f, h1 = 0.0f;
    float impreg = 0.0f;

    __syncthreads();   // sWhh ready

    for (int t = 0; t < NT; ++t) {
        const int tt = dir ? (NT - 1 - t) : t;   // bwd consumes reversed time
        float x = inp_b[tt];                      // channel 0
        const float m = inp_b[2 * NT + tt];       // channel 2
        const float d = inp_b[3 * NT + tt];       // channel 3
        x = (x != x) ? -1.0f : x;                 // NaN -> -1

        // temporal decay gamma
        h0 *= fsig(d * gw0 + gb0);
        h1 *= fsig(d * gw1 + gb1);

        // publish post-gamma h for the matvec
        hbuf[t & 1][sidx][j2]      = h0;
        hbuf[t & 1][sidx][j2 + 32] = h1;

        // x_h = h . rW + rb  (reduce over the 32 lanes of this half-wave)
        float part = h0 * rw0 + h1 * rw1;
        part += __shfl_xor(part, 1);
        part += __shfl_xor(part, 2);
        part += __shfl_xor(part, 4);
        part += __shfl_xor(part, 8);
        part += __shfl_xor(part, 16);
        const float x_h = part + rbv;
        impreg = ((t & 31) == j2) ? x_h : impreg;   // buffer imputation output
        const float x_c = m * x + (1.0f - m) * x_h;

        __syncthreads();

        // gh rows: 6 dot products of length 64 from LDS
        float acc0 = 0, acc1 = 0, acc2 = 0, acc3 = 0, acc4 = 0, acc5 = 0;
        const float4* hv4 = (const float4*)&hbuf[t & 1][sidx][0];
#pragma unroll
        for (int q = 0; q < 16; ++q) {
            const float4 hv = hv4[q];
            const float4 w0 = *(const float4*)&sWhh[rowoff[0] + q * 4];
            const float4 w1 = *(const float4*)&sWhh[rowoff[1] + q * 4];
            const float4 w2 = *(const float4*)&sWhh[rowoff[2] + q * 4];
            const float4 w3 = *(const float4*)&sWhh[rowoff[3] + q * 4];
            const float4 w4 = *(const float4*)&sWhh[rowoff[4] + q * 4];
            const float4 w5 = *(const float4*)&sWhh[rowoff[5] + q * 4];
            acc0 += hv.x * w0.x + hv.y * w0.y + hv.z * w0.z + hv.w * w0.w;
            acc1 += hv.x * w1.x + hv.y * w1.y + hv.z * w1.z + hv.w * w1.w;
            acc2 += hv.x * w2.x + hv.y * w2.y + hv.z * w2.z + hv.w * w2.w;
            acc3 += hv.x * w3.x + hv.y * w3.y + hv.z * w3.z + hv.w * w3.w;
            acc4 += hv.x * w4.x + hv.y * w4.y + hv.z * w4.z + hv.w * w4.w;
            acc5 += hv.x * w5.x + hv.y * w5.y + hv.z * w5.z + hv.w * w5.w;
        }

        // GRU gates
        const float r0 = fsig(x_c * wx[0] + m * wm[0] + bs0 + acc0);
        const float r1 = fsig(x_c * wx[1] + m * wm[1] + bs1 + acc1);
        const float z0 = fsig(x_c * wx[2] + m * wm[2] + bs2 + acc2);
        const float z1 = fsig(x_c * wx[3] + m * wm[3] + bs3 + acc3);
        const float n0 = ftanh(x_c * wx[4] + m * wm[4] + bihN0 + r0 * (acc4 + bhhN0));
        const float n1 = ftanh(x_c * wx[5] + m * wm[5] + bihN1 + r1 * (acc5 + bhhN1));
        h0 = (1.0f - z0) * n0 + z0 * h0;
        h1 = (1.0f - z1) * n1 + z1 * h1;

        // coalesced flush of 32 buffered imputation values
        if ((t & 31) == 31) {
            impOut[(t - 31) + j2] = impreg;
        }
    }

    // final hidden -> fc partial (fcb folded in); combined by second kernel
    const float fw0 = fcW[jA], fw1 = fcW[jB];
    float p = h0 * fw0 + h1 * fw1;
    p += __shfl_xor(p, 1);
    p += __shfl_xor(p, 2);
    p += __shfl_xor(p, 4);
    p += __shfl_xor(p, 8);
    p += __shfl_xor(p, 16);
    if (j2 == 0) ws[dir * 2048 + batch] = p + fcb[0];
}

__global__ void brits_combine(const float* __restrict__ ws, float* __restrict__ out)
{
    int i = blockIdx.x * 256 + threadIdx.x;
    if (i < 2048) out[i] = 0.5f * (ws[i] + ws[2048 + i]);
}

extern "C" void kernel_launch(void* const* d_in, const int* in_sizes, int n_in,
                              void* d_out, int out_size, void* d_ws, size_t ws_size,
                              hipStream_t stream)
{
    const float* p[21];
    for (int i = 0; i < 21; ++i) p[i] = (const float*)d_in[i];
    float* out = (float*)d_out;
    float* ws  = (float*)d_ws;   // 4096 floats used

    brits_rnn<<<512, 256, 0, stream>>>(
        p[0],
        p[1], p[2], p[3], p[4], p[5], p[6], p[7], p[8], p[9], p[10],
        p[11], p[12], p[13], p[14], p[15], p[16], p[17], p[18], p[19], p[20],
        out, ws);
    brits_combine<<<8, 256, 0, stream>>>(ws, out);
}

// Round 4
// 581.419 us; speedup vs baseline: 4.5713x; 4.5713x over previous
//
#include <hip/hip_runtime.h>

#define NT   512
#define IMPN (2048 * 512)
#define HROW 72                      // ushorts per h_lds seq-row (144 B): pad for bank spread

typedef __attribute__((ext_vector_type(8))) short short8v;
typedef __attribute__((ext_vector_type(4))) float f32x4;

union Frag { short8v v; unsigned short s[8]; };

__device__ __forceinline__ float fsig(float x) {
    return __builtin_amdgcn_rcpf(1.0f + __expf(-x));
}
__device__ __forceinline__ float ftanh(float x) {
    return 2.0f * __builtin_amdgcn_rcpf(1.0f + __expf(-2.0f * x)) - 1.0f;
}
// fp32 -> bf16 RNE, and exact back-conversion
__device__ __forceinline__ unsigned short f2bf(float f) {
    unsigned u = __float_as_uint(f);
    unsigned r = u + 0x7FFFu + ((u >> 16) & 1u);
    return (unsigned short)(r >> 16);
}
__device__ __forceinline__ float bf2f(unsigned short s) {
    return __uint_as_float(((unsigned)s) << 16);
}

// 256 blocks x 256 threads. Blocks 0..127 fwd, 128..255 bwd; block = 16 seqs.
// Wave w owns units u = 16w + (lane&15); gate rows {u, 64+u, 128+u} as register
// bf16 3-level (H/M/L) B-fragments. h carried fp32 in registers (C-layout:
// lane(g,j) holds seqs 4g+q, unit u), republished per step as 3 bf16 LDS planes.
// MFMA 16x16x32: D[seq][unit], seq=(lane>>4)*4+reg, col=lane&15.
// acc3 = xh (B = rW broadcast over cols), 6-product 3-level split per target.
// dir=1 consumes time REVERSED (scan tau -> data time NT-1-tau); imp stored at
// scan index (reference impB is in scan order).
__global__ __launch_bounds__(256, 1) void brits_mfma(
    const float* __restrict__ input,
    const float* __restrict__ gW_f, const float* __restrict__ gb_f,
    const float* __restrict__ rW_f, const float* __restrict__ rb_f,
    const float* __restrict__ fcW_f, const float* __restrict__ fcb_f,
    const float* __restrict__ Wih_f, const float* __restrict__ bih_f,
    const float* __restrict__ Whh_f, const float* __restrict__ bhh_f,
    const float* __restrict__ gW_b, const float* __restrict__ gb_b,
    const float* __restrict__ rW_b, const float* __restrict__ rb_b,
    const float* __restrict__ fcW_b, const float* __restrict__ fcb_b,
    const float* __restrict__ Wih_b, const float* __restrict__ bih_b,
    const float* __restrict__ Whh_b, const float* __restrict__ bhh_b,
    float* __restrict__ out, float* __restrict__ ws)
{
    __shared__ __align__(16) unsigned short h_lds[2][3][16 * HROW]; // [buf][lev][seq*HROW+unit]
    __shared__ __align__(16) float xmd_l[3 * 256];                  // [ch'][s*16+tau]
    __shared__ __align__(16) float impbuf[16][17];
    __shared__ __align__(16) float fcpart[16][4];

    const int tid  = threadIdx.x;
    const int w    = tid >> 6;
    const int lane = tid & 63;
    const int j    = lane & 15;
    const int g    = lane >> 4;
    const int u    = w * 16 + j;
    const int dir  = blockIdx.x >> 7;
    const int b0   = (blockIdx.x & 127) * 16;

    const float* gW  = dir ? gW_b  : gW_f;
    const float* gb  = dir ? gb_b  : gb_f;
    const float* rW  = dir ? rW_b  : rW_f;
    const float* rb  = dir ? rb_b  : rb_f;
    const float* fcW = dir ? fcW_b : fcW_f;
    const float* fcb = dir ? fcb_b : fcb_f;
    const float* Wih = dir ? Wih_b : Wih_f;
    const float* bih = dir ? bih_b : bih_f;
    const float* Whh = dir ? Whh_b : Whh_f;
    const float* bhh = dir ? bhh_b : bhh_f;

    // per-lane scalar constants
    const float gWu = gW[u], gbu = gb[u], fcWu = fcW[u];
    const int Rr = u, Rz = 64 + u, Rn = 128 + u;
    const float wxr = Wih[2 * Rr], wmr = Wih[2 * Rr + 1];
    const float wxz = Wih[2 * Rz], wmz = Wih[2 * Rz + 1];
    const float wxn = Wih[2 * Rn], wmn = Wih[2 * Rn + 1];
    const float br  = bih[Rr] + bhh[Rr];
    const float bz  = bih[Rz] + bhh[Rz];
    const float bin = bih[Rn], bhn = bhh[Rn];
    const float rb0 = rb[0];

    // B fragments: 4 targets (r,z,n,xh) x 2 k-tiles x 3 levels, registers.
    // target t<3: B[k][col j] = Whh[t*64+u][k]; t==3: B[k][*] = rW[k] (broadcast).
    Frag B[4][2][3];
#pragma unroll
    for (int t = 0; t < 4; ++t) {
        const float* src = (t < 3) ? (Whh + (t * 64 + u) * 64) : rW;
#pragma unroll
        for (int kt = 0; kt < 2; ++kt) {
#pragma unroll
            for (int e = 0; e < 8; ++e) {
                const float v = src[kt * 32 + g * 8 + e];
                const unsigned short bH = f2bf(v);
                const float fH = bf2f(bH);
                const float vm = v - fH;                 // exact (Sterbenz)
                const unsigned short bM = f2bf(vm);
                const float fM = bf2f(bM);
                const unsigned short bL = f2bf(vm - fM); // RNE residual
                B[t][kt][0].s[e] = bH;
                B[t][kt][1].s[e] = bM;
                B[t][kt][2].s[e] = bL;
            }
        }
    }

    const float* inp = input + (size_t)b0 * 3072;
    float* impOut = out + 2048 + (size_t)dir * IMPN + (size_t)b0 * NT;

    float h[4] = {0.0f, 0.0f, 0.0f, 0.0f};

    for (int t = 0; t < NT; ++t) {
        const int tm = t & 15;
        if (tm == 0) {                            // 16-step chunk boundary
            __syncthreads();
            if (t > 0) {                          // coalesced imp flush
                const int fs = tid >> 4, ft = tid & 15;
                impOut[fs * NT + (t - 16) + ft] = impbuf[fs][ft];
            }
            if (tid < 192) {                      // stage x/m/d chunk (scan order)
                const int s = tid / 12, r2 = tid - s * 12, c = r2 >> 2, grp = r2 & 3;
                const int cho = (c == 0) ? 0 : ((c == 1) ? 2 * NT : 3 * NT);
                const float* base = inp + (size_t)s * 3072 + cho;
                float4 v;
                if (dir == 0) {
                    v = *(const float4*)(base + t + grp * 4);
                } else {
                    // scan tau = t+grp*4+e -> data time NT-1-tau; reversed load
                    float4 r = *(const float4*)(base + (NT - 4 - t - grp * 4));
                    v.x = r.w; v.y = r.z; v.z = r.y; v.w = r.x;
                }
                if (c == 0) {
                    v.x = (v.x != v.x) ? -1.0f : v.x;
                    v.y = (v.y != v.y) ? -1.0f : v.y;
                    v.z = (v.z != v.z) ? -1.0f : v.z;
                    v.w = (v.w != v.w) ? -1.0f : v.w;
                }
                *(float4*)&xmd_l[c * 256 + s * 16 + grp * 4] = v;
            }
            __syncthreads();
        }
        const int buf = t & 1;

        // ---- phase A: decay + 3-level split + publish to LDS ----
#pragma unroll
        for (int q = 0; q < 4; ++q) {
            const int s = 4 * g + q;
            const float dv = xmd_l[512 + s * 16 + tm];
            const float x = h[q] * fsig(dv * gWu + gbu);
            h[q] = x;                                  // post-decay h (used by update)
            const unsigned short bH = f2bf(x);
            const float fH = bf2f(bH);
            const float xm = x - fH;
            const unsigned short bM = f2bf(xm);
            const float fM = bf2f(bM);
            const unsigned short bL = f2bf(xm - fM);
            h_lds[buf][0][s * HROW + u] = bH;
            h_lds[buf][1][s * HROW + u] = bM;
            h_lds[buf][2][s * HROW + u] = bL;
        }
        __syncthreads();

        // ---- phase B: A-frags (bf16 direct) + 48 MFMA ----
        Frag A[2][3];
#pragma unroll
        for (int kt = 0; kt < 2; ++kt)
#pragma unroll
            for (int lev = 0; lev < 3; ++lev)
                A[kt][lev].v = *(const short8v*)&h_lds[buf][lev][j * HROW + kt * 32 + 8 * g];

        f32x4 acc0 = {0,0,0,0}, acc1 = {0,0,0,0}, acc2 = {0,0,0,0}, acc3 = {0,0,0,0};
#pragma unroll
        for (int kt = 0; kt < 2; ++kt) {
            // 6-product 3-level scheme, interleaved across the 4 accumulators
            acc0 = __builtin_amdgcn_mfma_f32_16x16x32_bf16(A[kt][0].v, B[0][kt][0].v, acc0, 0, 0, 0);
            acc1 = __builtin_amdgcn_mfma_f32_16x16x32_bf16(A[kt][0].v, B[1][kt][0].v, acc1, 0, 0, 0);
            acc2 = __builtin_amdgcn_mfma_f32_16x16x32_bf16(A[kt][0].v, B[2][kt][0].v, acc2, 0, 0, 0);
            acc3 = __builtin_amdgcn_mfma_f32_16x16x32_bf16(A[kt][0].v, B[3][kt][0].v, acc3, 0, 0, 0);
            acc0 = __builtin_amdgcn_mfma_f32_16x16x32_bf16(A[kt][1].v, B[0][kt][0].v, acc0, 0, 0, 0);
            acc1 = __builtin_amdgcn_mfma_f32_16x16x32_bf16(A[kt][1].v, B[1][kt][0].v, acc1, 0, 0, 0);
            acc2 = __builtin_amdgcn_mfma_f32_16x16x32_bf16(A[kt][1].v, B[2][kt][0].v, acc2, 0, 0, 0);
            acc3 = __builtin_amdgcn_mfma_f32_16x16x32_bf16(A[kt][1].v, B[3][kt][0].v, acc3, 0, 0, 0);
            acc0 = __builtin_amdgcn_mfma_f32_16x16x32_bf16(A[kt][0].v, B[0][kt][1].v, acc0, 0, 0, 0);
            acc1 = __builtin_amdgcn_mfma_f32_16x16x32_bf16(A[kt][0].v, B[1][kt][1].v, acc1, 0, 0, 0);
            acc2 = __builtin_amdgcn_mfma_f32_16x16x32_bf16(A[kt][0].v, B[2][kt][1].v, acc2, 0, 0, 0);
            acc3 = __builtin_amdgcn_mfma_f32_16x16x32_bf16(A[kt][0].v, B[3][kt][1].v, acc3, 0, 0, 0);
            acc0 = __builtin_amdgcn_mfma_f32_16x16x32_bf16(A[kt][2].v, B[0][kt][0].v, acc0, 0, 0, 0);
            acc1 = __builtin_amdgcn_mfma_f32_16x16x32_bf16(A[kt][2].v, B[1][kt][0].v, acc1, 0, 0, 0);
            acc2 = __builtin_amdgcn_mfma_f32_16x16x32_bf16(A[kt][2].v, B[2][kt][0].v, acc2, 0, 0, 0);
            acc3 = __builtin_amdgcn_mfma_f32_16x16x32_bf16(A[kt][2].v, B[3][kt][0].v, acc3, 0, 0, 0);
            acc0 = __builtin_amdgcn_mfma_f32_16x16x32_bf16(A[kt][0].v, B[0][kt][2].v, acc0, 0, 0, 0);
            acc1 = __builtin_amdgcn_mfma_f32_16x16x32_bf16(A[kt][0].v, B[1][kt][2].v, acc1, 0, 0, 0);
            acc2 = __builtin_amdgcn_mfma_f32_16x16x32_bf16(A[kt][0].v, B[2][kt][2].v, acc2, 0, 0, 0);
            acc3 = __builtin_amdgcn_mfma_f32_16x16x32_bf16(A[kt][0].v, B[3][kt][2].v, acc3, 0, 0, 0);
            acc0 = __builtin_amdgcn_mfma_f32_16x16x32_bf16(A[kt][1].v, B[0][kt][1].v, acc0, 0, 0, 0);
            acc1 = __builtin_amdgcn_mfma_f32_16x16x32_bf16(A[kt][1].v, B[1][kt][1].v, acc1, 0, 0, 0);
            acc2 = __builtin_amdgcn_mfma_f32_16x16x32_bf16(A[kt][1].v, B[2][kt][1].v, acc2, 0, 0, 0);
            acc3 = __builtin_amdgcn_mfma_f32_16x16x32_bf16(A[kt][1].v, B[3][kt][1].v, acc3, 0, 0, 0);
        }

        // ---- phase C: gates (all in-register; C-layout == gate-row layout) ----
#pragma unroll
        for (int q = 0; q < 4; ++q) {
            const int s = 4 * g + q;
            const float xv = xmd_l[s * 16 + tm];
            const float mv = xmd_l[256 + s * 16 + tm];
            const float xh = acc3[q] + rb0;
            if (w == 0 && j == 0) impbuf[s][tm] = xh;
            const float xc = mv * xv + (1.0f - mv) * xh;
            const float rr = fsig(acc0[q] + wxr * xc + wmr * mv + br);
            const float zz = fsig(acc1[q] + wxz * xc + wmz * mv + bz);
            const float nn = ftanh(wxn * xc + wmn * mv + bin + rr * (acc2[q] + bhn));
            h[q] = (1.0f - zz) * nn + zz * h[q];
        }
    }

    // epilogue: flush last imp chunk + fc reduction
    __syncthreads();
    {
        const int fs = tid >> 4, ft = tid & 15;
        impOut[fs * NT + (NT - 16) + ft] = impbuf[fs][ft];
    }
    float p2[4];
#pragma unroll
    for (int q = 0; q < 4; ++q) {
        p2[q] = h[q] * fcWu;
        p2[q] += __shfl_xor(p2[q], 1);
        p2[q] += __shfl_xor(p2[q], 2);
        p2[q] += __shfl_xor(p2[q], 4);
        p2[q] += __shfl_xor(p2[q], 8);
    }
    if (j == 0) {
#pragma unroll
        for (int q = 0; q < 4; ++q) fcpart[4 * g + q][w] = p2[q];
    }
    __syncthreads();
    if (tid < 16) {
        float4 xp = *(const float4*)&fcpart[tid][0];
        ws[dir * 2048 + b0 + tid] = xp.x + xp.y + xp.z + xp.w + fcb[0];
    }
}

__global__ void brits_combine(const float* __restrict__ ws, float* __restrict__ out)
{
    int i = blockIdx.x * 256 + threadIdx.x;
    if (i < 2048) out[i] = 0.5f * (ws[i] + ws[2048 + i]);
}

extern "C" void kernel_launch(void* const* d_in, const int* in_sizes, int n_in,
                              void* d_out, int out_size, void* d_ws, size_t ws_size,
                              hipStream_t stream)
{
    const float* p[21];
    for (int i = 0; i < 21; ++i) p[i] = (const float*)d_in[i];
    float* out = (float*)d_out;
    float* ws  = (float*)d_ws;   // 4096 floats used

    brits_mfma<<<256, 256, 0, stream>>>(
        p[0],
        p[1], p[2], p[3], p[4], p[5], p[6], p[7], p[8], p[9], p[10],
        p[11], p[12], p[13], p[14], p[15], p[16], p[17], p[18], p[19], p[20],
        out, ws);
    brits_combine<<<8, 256, 0, stream>>>(ws, out);
}

// Round 5
// 474.532 us; speedup vs baseline: 5.6009x; 1.2252x over previous
//
#include <hip/hip_runtime.h>

#define NT   512
#define IMPN (2048 * 512)
#define HROW 72                      // ushorts per h_lds seq-row (144 B): pad for bank spread

typedef __attribute__((ext_vector_type(8))) short short8v;
typedef __attribute__((ext_vector_type(4))) float f32x4;

union Frag { short8v v; unsigned short s[8]; };

__device__ __forceinline__ float fsig(float x) {
    return __builtin_amdgcn_rcpf(1.0f + __expf(-x));
}
__device__ __forceinline__ float ftanh(float x) {
    return 2.0f * __builtin_amdgcn_rcpf(1.0f + __expf(-2.0f * x)) - 1.0f;
}
// fp32 -> bf16 RNE, and exact back-conversion
__device__ __forceinline__ unsigned short f2bf(float f) {
    unsigned u = __float_as_uint(f);
    unsigned r = u + 0x7FFFu + ((u >> 16) & 1u);
    return (unsigned short)(r >> 16);
}
__device__ __forceinline__ float bf2f(unsigned short s) {
    return __uint_as_float(((unsigned)s) << 16);
}

// 256 blocks x 256 threads. Blocks 0..127 fwd, 128..255 bwd; block = 16 seqs.
// Wave w owns units u = 16w + (lane&15); gate rows {u, 64+u, 128+u} as register
// bf16 2-level (H/L) B-fragments. h carried fp32 in registers (C-layout:
// lane(g,j) holds seqs 4g+q, unit u), republished per step as 2 bf16 LDS planes.
// MFMA 16x16x32: D[seq][unit], seq=(lane>>4)*4+reg, col=lane&15.
// acc3 = xh (B = rW broadcast over cols). 3-product scheme {HH, LH, HL} per
// target: per-product err ~3*2^-16; GRU update is contractive (z<1, decay<1)
// so final err ~ few e-4, well under the 7.5e-3 threshold (bf16 floor 2^-9).
// dir=1 consumes time REVERSED (scan tau -> data time NT-1-tau); imp stored at
// scan index (reference impB is in scan order).
__global__ __launch_bounds__(256, 1) void brits_mfma(
    const float* __restrict__ input,
    const float* __restrict__ gW_f, const float* __restrict__ gb_f,
    const float* __restrict__ rW_f, const float* __restrict__ rb_f,
    const float* __restrict__ fcW_f, const float* __restrict__ fcb_f,
    const float* __restrict__ Wih_f, const float* __restrict__ bih_f,
    const float* __restrict__ Whh_f, const float* __restrict__ bhh_f,
    const float* __restrict__ gW_b, const float* __restrict__ gb_b,
    const float* __restrict__ rW_b, const float* __restrict__ rb_b,
    const float* __restrict__ fcW_b, const float* __restrict__ fcb_b,
    const float* __restrict__ Wih_b, const float* __restrict__ bih_b,
    const float* __restrict__ Whh_b, const float* __restrict__ bhh_b,
    float* __restrict__ out, float* __restrict__ ws)
{
    __shared__ __align__(16) unsigned short h_lds[2][2][16 * HROW]; // [buf][lev][seq*HROW+unit]
    __shared__ __align__(16) float xmd_l[3 * 256];                  // [ch'][s*16+tau]
    __shared__ __align__(16) float impbuf[16][17];
    __shared__ __align__(16) float fcpart[16][4];

    const int tid  = threadIdx.x;
    const int w    = tid >> 6;
    const int lane = tid & 63;
    const int j    = lane & 15;
    const int g    = lane >> 4;
    const int u    = w * 16 + j;
    const int dir  = blockIdx.x >> 7;
    const int b0   = (blockIdx.x & 127) * 16;

    const float* gW  = dir ? gW_b  : gW_f;
    const float* gb  = dir ? gb_b  : gb_f;
    const float* rW  = dir ? rW_b  : rW_f;
    const float* rb  = dir ? rb_b  : rb_f;
    const float* fcW = dir ? fcW_b : fcW_f;
    const float* fcb = dir ? fcb_b : fcb_f;
    const float* Wih = dir ? Wih_b : Wih_f;
    const float* bih = dir ? bih_b : bih_f;
    const float* Whh = dir ? Whh_b : Whh_f;
    const float* bhh = dir ? bhh_b : bhh_f;

    // per-lane scalar constants
    const float gWu = gW[u], gbu = gb[u], fcWu = fcW[u];
    const int Rr = u, Rz = 64 + u, Rn = 128 + u;
    const float wxr = Wih[2 * Rr], wmr = Wih[2 * Rr + 1];
    const float wxz = Wih[2 * Rz], wmz = Wih[2 * Rz + 1];
    const float wxn = Wih[2 * Rn], wmn = Wih[2 * Rn + 1];
    const float br  = bih[Rr] + bhh[Rr];
    const float bz  = bih[Rz] + bhh[Rz];
    const float bin = bih[Rn], bhn = bhh[Rn];
    const float rb0 = rb[0];

    // B fragments: 4 targets (r,z,n,xh) x 2 k-tiles x 2 levels, registers.
    // target t<3: B[k][col j] = Whh[t*64+u][k]; t==3: B[k][*] = rW[k] (broadcast).
    Frag B[4][2][2];
#pragma unroll
    for (int t = 0; t < 4; ++t) {
        const float* src = (t < 3) ? (Whh + (t * 64 + u) * 64) : rW;
#pragma unroll
        for (int kt = 0; kt < 2; ++kt) {
#pragma unroll
            for (int e = 0; e < 8; ++e) {
                const float v = src[kt * 32 + g * 8 + e];
                const unsigned short bH = f2bf(v);
                const unsigned short bL = f2bf(v - bf2f(bH));  // RNE residual
                B[t][kt][0].s[e] = bH;
                B[t][kt][1].s[e] = bL;
            }
        }
    }

    const float* inp = input + (size_t)b0 * 3072;
    float* impOut = out + 2048 + (size_t)dir * IMPN + (size_t)b0 * NT;

    float h[4] = {0.0f, 0.0f, 0.0f, 0.0f};

    for (int t = 0; t < NT; ++t) {
        const int tm = t & 15;
        if (tm == 0) {                            // 16-step chunk boundary
            __syncthreads();
            if (t > 0) {                          // coalesced imp flush
                const int fs = tid >> 4, ft = tid & 15;
                impOut[fs * NT + (t - 16) + ft] = impbuf[fs][ft];
            }
            if (tid < 192) {                      // stage x/m/d chunk (scan order)
                const int s = tid / 12, r2 = tid - s * 12, c = r2 >> 2, grp = r2 & 3;
                const int cho = (c == 0) ? 0 : ((c == 1) ? 2 * NT : 3 * NT);
                const float* base = inp + (size_t)s * 3072 + cho;
                float4 v;
                if (dir == 0) {
                    v = *(const float4*)(base + t + grp * 4);
                } else {
                    // scan tau = t+grp*4+e -> data time NT-1-tau; reversed load
                    float4 r = *(const float4*)(base + (NT - 4 - t - grp * 4));
                    v.x = r.w; v.y = r.z; v.z = r.y; v.w = r.x;
                }
                if (c == 0) {
                    v.x = (v.x != v.x) ? -1.0f : v.x;
                    v.y = (v.y != v.y) ? -1.0f : v.y;
                    v.z = (v.z != v.z) ? -1.0f : v.z;
                    v.w = (v.w != v.w) ? -1.0f : v.w;
                }
                *(float4*)&xmd_l[c * 256 + s * 16 + grp * 4] = v;
            }
            __syncthreads();
        }
        const int buf = t & 1;

        // ---- phase A: decay + 2-level split + publish to LDS ----
#pragma unroll
        for (int q = 0; q < 4; ++q) {
            const int s = 4 * g + q;
            const float dv = xmd_l[512 + s * 16 + tm];
            const float x = h[q] * fsig(dv * gWu + gbu);
            h[q] = x;                                  // post-decay h (used by update)
            const unsigned short bH = f2bf(x);
            const unsigned short bL = f2bf(x - bf2f(bH));
            h_lds[buf][0][s * HROW + u] = bH;
            h_lds[buf][1][s * HROW + u] = bL;
        }
        __syncthreads();

        // ---- phase B: A-frags (bf16 direct) + 24 MFMA, acc3 (xh) first ----
        Frag A[2][2];
#pragma unroll
        for (int kt = 0; kt < 2; ++kt)
#pragma unroll
            for (int lev = 0; lev < 2; ++lev)
                A[kt][lev].v = *(const short8v*)&h_lds[buf][lev][j * HROW + kt * 32 + 8 * g];

        f32x4 acc0 = {0,0,0,0}, acc1 = {0,0,0,0}, acc2 = {0,0,0,0}, acc3 = {0,0,0,0};
#pragma unroll
        for (int kt = 0; kt < 2; ++kt) {
            // 3-product {HH, LH, HL}, rotation (3,0,2,1): xh finishes first,
            // z last, so the phase-C VALU chain overlaps the MFMA tail.
            acc3 = __builtin_amdgcn_mfma_f32_16x16x32_bf16(A[kt][0].v, B[3][kt][0].v, acc3, 0, 0, 0);
            acc0 = __builtin_amdgcn_mfma_f32_16x16x32_bf16(A[kt][0].v, B[0][kt][0].v, acc0, 0, 0, 0);
            acc2 = __builtin_amdgcn_mfma_f32_16x16x32_bf16(A[kt][0].v, B[2][kt][0].v, acc2, 0, 0, 0);
            acc1 = __builtin_amdgcn_mfma_f32_16x16x32_bf16(A[kt][0].v, B[1][kt][0].v, acc1, 0, 0, 0);
            acc3 = __builtin_amdgcn_mfma_f32_16x16x32_bf16(A[kt][1].v, B[3][kt][0].v, acc3, 0, 0, 0);
            acc0 = __builtin_amdgcn_mfma_f32_16x16x32_bf16(A[kt][1].v, B[0][kt][0].v, acc0, 0, 0, 0);
            acc2 = __builtin_amdgcn_mfma_f32_16x16x32_bf16(A[kt][1].v, B[2][kt][0].v, acc2, 0, 0, 0);
            acc1 = __builtin_amdgcn_mfma_f32_16x16x32_bf16(A[kt][1].v, B[1][kt][0].v, acc1, 0, 0, 0);
            acc3 = __builtin_amdgcn_mfma_f32_16x16x32_bf16(A[kt][0].v, B[3][kt][1].v, acc3, 0, 0, 0);
            acc0 = __builtin_amdgcn_mfma_f32_16x16x32_bf16(A[kt][0].v, B[0][kt][1].v, acc0, 0, 0, 0);
            acc2 = __builtin_amdgcn_mfma_f32_16x16x32_bf16(A[kt][0].v, B[2][kt][1].v, acc2, 0, 0, 0);
            acc1 = __builtin_amdgcn_mfma_f32_16x16x32_bf16(A[kt][0].v, B[1][kt][1].v, acc1, 0, 0, 0);
        }

        // ---- phase C: gates (all in-register; C-layout == gate-row layout) ----
#pragma unroll
        for (int q = 0; q < 4; ++q) {
            const int s = 4 * g + q;
            const float xv = xmd_l[s * 16 + tm];
            const float mv = xmd_l[256 + s * 16 + tm];
            const float xh = acc3[q] + rb0;
            if (w == 0 && j == 0) impbuf[s][tm] = xh;
            const float xc = mv * xv + (1.0f - mv) * xh;
            const float rr = fsig(acc0[q] + wxr * xc + wmr * mv + br);
            const float zz = fsig(acc1[q] + wxz * xc + wmz * mv + bz);
            const float nn = ftanh(wxn * xc + wmn * mv + bin + rr * (acc2[q] + bhn));
            h[q] = (1.0f - zz) * nn + zz * h[q];
        }
    }

    // epilogue: flush last imp chunk + fc reduction
    __syncthreads();
    {
        const int fs = tid >> 4, ft = tid & 15;
        impOut[fs * NT + (NT - 16) + ft] = impbuf[fs][ft];
    }
    float p2[4];
#pragma unroll
    for (int q = 0; q < 4; ++q) {
        p2[q] = h[q] * fcWu;
        p2[q] += __shfl_xor(p2[q], 1);
        p2[q] += __shfl_xor(p2[q], 2);
        p2[q] += __shfl_xor(p2[q], 4);
        p2[q] += __shfl_xor(p2[q], 8);
    }
    if (j == 0) {
#pragma unroll
        for (int q = 0; q < 4; ++q) fcpart[4 * g + q][w] = p2[q];
    }
    __syncthreads();
    if (tid < 16) {
        float4 xp = *(const float4*)&fcpart[tid][0];
        ws[dir * 2048 + b0 + tid] = xp.x + xp.y + xp.z + xp.w + fcb[0];
    }
}

__global__ void brits_combine(const float* __restrict__ ws, float* __restrict__ out)
{
    int i = blockIdx.x * 256 + threadIdx.x;
    if (i < 2048) out[i] = 0.5f * (ws[i] + ws[2048 + i]);
}

extern "C" void kernel_launch(void* const* d_in, const int* in_sizes, int n_in,
                              void* d_out, int out_size, void* d_ws, size_t ws_size,
                              hipStream_t stream)
{
    const float* p[21];
    for (int i = 0; i < 21; ++i) p[i] = (const float*)d_in[i];
    float* out = (float*)d_out;
    float* ws  = (float*)d_ws;   // 4096 floats used

    brits_mfma<<<256, 256, 0, stream>>>(
        p[0],
        p[1], p[2], p[3], p[4], p[5], p[6], p[7], p[8], p[9], p[10],
        p[11], p[12], p[13], p[14], p[15], p[16], p[17], p[18], p[19], p[20],
        out, ws);
    brits_combine<<<8, 256, 0, stream>>>(ws, out);
}